// Round 5
// baseline (398.959 us; speedup 1.0000x reference)
//
#include <hip/hip_runtime.h>
#include <hip/hip_cooperative_groups.h>
#include <math.h>

namespace cg = cooperative_groups;

typedef _Float16 f16;
typedef _Float16 f16x8 __attribute__((ext_vector_type(8)));
typedef _Float16 f16x4 __attribute__((ext_vector_type(4)));
typedef float    f32x4 __attribute__((ext_vector_type(4)));

#define BATCH 32
#define TT    600
#define CC    64
#define SEG   50
#define HH    512
#define G4    2048
#define FF    2144   // IN_SIZE = 64 + 2080
#define MM    1600   // BATCH*SEG
#define MP    1664   // padded: 52*32 (s-major) = 26*64 M-tiles
#define NPAIR 2016   // C*(C-1)/2
#define SLOT32 16384 // u32 words per h slot (32*512 elements, 1 tagged u32 each)

struct TV { int v[51]; };

// async global->LDS, 16B per lane. LDS dest must be wave-uniform base + lane*16.
__device__ __forceinline__ void async_copy16(char* lds, const char* g) {
  __builtin_amdgcn_global_load_lds(
      (const __attribute__((address_space(1))) unsigned int*)g,
      (__attribute__((address_space(3))) unsigned int*)lds, 16, 0, 0);
}

__device__ __forceinline__ float sigm(float x) { return 1.f / (1.f + __expf(-x)); }
__device__ __forceinline__ float tanh_(float x) {
  float ax = fabsf(x);
  float e  = __expf(2.f * ax);
  float t  = 1.f - 2.f / (e + 1.f);   // robust for large |x|
  return x < 0.f ? -t : t;
}
__device__ __forceinline__ unsigned int f16_bits(f16 v) {
  union { f16 f; unsigned short u; } c; c.f = v; return (unsigned int)c.u;
}

// ---------------- kernel 1: fp16 weight conversion (vectorized) ----------------
__global__ void convert_kernel(const float4* __restrict__ w_ih, const float4* __restrict__ w_hh,
                               f16x4* __restrict__ w16, f16x4* __restrict__ whh16) {
  int gtid = blockIdx.x * 256 + threadIdx.x;
  int nth  = gridDim.x * 256;
  for (int i = gtid; i < G4 * FF / 4; i += nth) {
    float4 v = w_ih[i];
    f16x4 o = {(f16)v.x, (f16)v.y, (f16)v.z, (f16)v.w};
    w16[i] = o;
  }
  for (int i = gtid; i < G4 * HH / 4; i += nth) {
    float4 v = w_hh[i];
    f16x4 o = {(f16)v.x, (f16)v.y, (f16)v.z, (f16)v.w};
    whh16[i] = o;
  }
}

// ---------------- kernel 2: segmented depth-2 log-signature -> fp16 feats ----
// s-major row layout: feature row m = s*32 + b
__global__ void feats_kernel(const float* __restrict__ x, f16* __restrict__ fhi, TV tv) {
  __shared__ float xs[13 * CC];
  int m   = blockIdx.x;
  int tid = threadIdx.x;
  f16* rhi = fhi + (size_t)m * FF;
  if (m >= MM) {              // zero-pad rows 1600..1663 (s = 50,51) for the GEMM M-edge
    unsigned int* a = (unsigned int*)rhi;
    for (int i = tid; i < FF / 2; i += 256) a[i] = 0u;
    return;
  }
  int bb = m & 31, ss = m >> 5;
  int t0 = tv.v[ss] - 1, t1 = tv.v[ss + 1] - 1;
  int len = t1 - t0;          // #intervals in segment (11..12)
  for (int i = tid; i < (len + 1) * CC; i += 256)
    xs[i] = x[(size_t)bb * TT * CC + (size_t)(t0 + (i >> 6)) * CC + (i & 63)];
  __syncthreads();

  if (tid < CC) {             // inc (cols 0..63) and xa (cols 2080..2143)
    float xa  = xs[tid];
    float inc = xs[len * CC + tid] - xa;
    rhi[tid] = (f16)inc;
    rhi[2080 + tid] = (f16)xa;
  }

  int p0 = tid * 8;           // 252 threads x 8 pairs = 2016 upper-tri pairs
  if (p0 < NPAIR) {
    int c = 0, rem = p0;
    while (rem >= 63 - c) { rem -= 63 - c; c++; }
    int d = c + 1 + rem;
    int cs[8], dd[8];
#pragma unroll
    for (int i = 0; i < 8; i++) {
      cs[i] = c; dd[i] = d;
      d++; if (d == 64) { c++; d = c + 1; }
    }
    float acc[8], xc[8], xd[8];
#pragma unroll
    for (int i = 0; i < 8; i++) { acc[i] = 0.f; xc[i] = xs[cs[i]]; xd[i] = xs[dd[i]]; }
    for (int t = 1; t <= len; t++) {
#pragma unroll
      for (int i = 0; i < 8; i++) {      // Levy area: sum x_c*dx_d - x_d*dx_c
        float nc = xs[t * CC + cs[i]], nd = xs[t * CC + dd[i]];
        acc[i] += xc[i] * (nd - xd[i]) - xd[i] * (nc - xc[i]);
        xc[i] = nc; xd[i] = nd;
      }
    }
#pragma unroll
    for (int i = 0; i < 8; i++) {
      int ci = cs[i], di = dd[i];
      float xac = xs[ci], xad = xs[di];
      float incc = xs[len * CC + ci] - xac, incd = xs[len * CC + di] - xad;
      float v = 0.5f * acc[i] - 0.5f * (xac * incd - xad * incc);
      rhi[64 + p0 + i] = (f16)v;
    }
  }
}

// ---------------- kernel 3: gx = feats @ w_ih^T + bias  (64x128 tiles, 416 blocks) ----
// XCD swizzle: per XCD, its 52 blocks cover all 26 M-tiles x 2 N-stripes -> B stays
// L2-resident. Wave wn owns a 64x32 sub-tile. Single fp16 pass.
__global__ __launch_bounds__(256) void gemm_kernel(
    const f16* __restrict__ fhi, const f16* __restrict__ w16,
    const float* __restrict__ bih, const float* __restrict__ bhh,
    float* __restrict__ gx) {
  __shared__ f16 smem[6 * 1024];   // A(4K) | B(8K)
  int tid  = threadIdx.x;
  int lane = tid & 63;
  int wn   = tid >> 6;

  int id = blockIdx.x;
  int x8 = id & 7;
  int j  = id >> 3;            // 0..51
  int mt = j % 26;
  int nt = (x8 << 1) | (j / 26);
  int m0 = mt * 64;
  int n0 = nt * 128;

  char* ldsA = (char*)&smem[0];
  char* ldsB = (char*)&smem[2048];

  int rowq = tid >> 2;            // 0..63
  int colq = (tid & 3) * 8;       // halves
  const f16* pa  = fhi + (size_t)(m0 + rowq) * FF + colq;
  const f16* pb0 = w16 + (size_t)(n0 + rowq) * FF + colq;
  const f16* pb1 = pb0 + (size_t)64 * FF;
  int ldst = tid * 16;

  f32x4 zero4 = {0.f, 0.f, 0.f, 0.f};
  f32x4 acc[4][2];
#pragma unroll
  for (int i = 0; i < 4; i++) { acc[i][0] = zero4; acc[i][1] = zero4; }

  int quad16 = (lane >> 4) * 16;  // byte offset of k-slice in a row
  int am = lane & 15;

  for (int kt = 0; kt < FF / 32; kt++) {
    int koff = kt * 32;
    async_copy16(ldsA + ldst,        (const char*)(pa + koff));
    async_copy16(ldsB + ldst,        (const char*)(pb0 + koff));
    async_copy16(ldsB + 4096 + ldst, (const char*)(pb1 + koff));
    __syncthreads();

    f16x8 bfr[2];
#pragma unroll
    for (int ni = 0; ni < 2; ni++)
      bfr[ni] = *(const f16x8*)(ldsB + (wn * 32 + ni * 16 + am) * 64 + quad16);
#pragma unroll
    for (int mi = 0; mi < 4; mi++) {
      f16x8 ah = *(const f16x8*)(ldsA + (mi * 16 + am) * 64 + quad16);
#pragma unroll
      for (int ni = 0; ni < 2; ni++)
        acc[mi][ni] = __builtin_amdgcn_mfma_f32_16x16x32_f16(ah, bfr[ni], acc[mi][ni], 0, 0, 0);
    }
    __syncthreads();
  }

#pragma unroll
  for (int ni = 0; ni < 2; ni++) {
    int ncol = n0 + wn * 32 + ni * 16 + (lane & 15);
    float bv = bih[ncol] + bhh[ncol];
#pragma unroll
    for (int mi = 0; mi < 4; mi++) {
      int mrow = m0 + mi * 16 + (lane >> 4) * 4;
#pragma unroll
      for (int r = 0; r < 4; r++)
        gx[(size_t)(mrow + r) * G4 + ncol] = acc[mi][ni][r] + bv;
    }
  }
}

// ---------------- kernel 4: persistent LSTM, tag-polling h exchange ----------------
// 32 WGs x 256 thr. WG owns 16 h-units; wave g computes gate g. w_hh fragments stay
// in VGPRs. h element = u32 (f16bits<<16 | step_tag) in a per-step 64KB slot (no
// reuse -> no ABA; ws poison 0xAAAA never matches tag<50). No flags, no grid sync.
// Staging: slot = 8192 u64; 256 threads x 32 u64, processed in TWO halves of 16
// (bounds VGPR pressure; half-1 producers finish while half-0 retries).
__global__ __launch_bounds__(256) void lstm_kernel(
    const float* __restrict__ gx, const f16* __restrict__ whh16,
    unsigned int* __restrict__ htag, float* __restrict__ out) {
  __shared__ f16 hs[BATCH * HH];         // 32 KB, layout [k8][b][8] fp16
  __shared__ float gbuf[4][BATCH][16];   // 8 KB gate exchange

  int tid  = threadIdx.x;
  int lane = tid & 63;
  int gate = tid >> 6;
  int u0   = blockIdx.x * 16;

  // preload w_hh fragments: B[k][n] = w_hh[n][k], n = gate*512 + u0 + (lane&15)
  f16x8 bf[16];
  {
    const f16* wrow = whh16 + (size_t)(gate * HH + u0 + (lane & 15)) * HH + (lane >> 4) * 8;
#pragma unroll
    for (int ks = 0; ks < 16; ks++) bf[ks] = *(const f16x8*)(wrow + ks * 32);
  }

  int b1 = tid >> 4;
  int ul = tid & 15;
  float cst0 = 0.f, cst1 = 0.f;
  int aq  = (lane >> 4);
  int am  = (lane & 15);
  int col = lane & 15;
  int rbase = (lane >> 4) * 4;

  for (int s = 0; s < SEG; s++) {
    // prefetch gx for this step (independent of h -> overlaps the poll)
    float gxr0[4], gxr1[4];
#pragma unroll
    for (int r = 0; r < 4; r++) {
      int b = rbase + r;
      gxr0[r] = gx[(size_t)((s << 5) + b) * G4 + gate * HH + u0 + col];
      gxr1[r] = gx[(size_t)((s << 5) + b + 16) * G4 + gate * HH + u0 + col];
    }

    f32x4 acc0 = {0.f, 0.f, 0.f, 0.f};
    f32x4 acc1 = {0.f, 0.f, 0.f, 0.f};

    if (s > 0) {
      // poll tagged h[s]: slot = 8192 u64; this thread covers u64 indices
      // {half*4096 + i*256 + tid : i<16, half<2}. Packed u32 LDS index == u64 index.
      const unsigned long long* hrd =
          (const unsigned long long*)(htag + (size_t)s * SLOT32);
      unsigned int tag = (unsigned int)s;
      unsigned int* hw = (unsigned int*)hs;
#pragma clang loop unroll(disable)
      for (int half = 0; half < 2; half++) {
        int base = half * 4096 + tid;
        unsigned long long v[16];
        unsigned int pend = 0;
#pragma unroll
        for (int i = 0; i < 16; i++)
          v[i] = __hip_atomic_load(hrd + base + i * 256, __ATOMIC_RELAXED,
                                   __HIP_MEMORY_SCOPE_AGENT);
#pragma unroll
        for (int i = 0; i < 16; i++) {
          unsigned int w0 = (unsigned int)v[i], w1 = (unsigned int)(v[i] >> 32);
          if (((w0 & 0xFFFFu) != tag) | ((w1 & 0xFFFFu) != tag)) pend |= (1u << i);
        }
        while (pend) {
#pragma unroll
          for (int i = 0; i < 16; i++)
            if (pend & (1u << i)) {
              unsigned long long t = __hip_atomic_load(hrd + base + i * 256,
                                                       __ATOMIC_RELAXED,
                                                       __HIP_MEMORY_SCOPE_AGENT);
              unsigned int w0 = (unsigned int)t, w1 = (unsigned int)(t >> 32);
              if (((w0 & 0xFFFFu) == tag) & ((w1 & 0xFFFFu) == tag)) {
                v[i] = t;
                pend &= ~(1u << i);
              }
            }
        }
#pragma unroll
        for (int i = 0; i < 16; i++) {
          unsigned int w0 = (unsigned int)v[i], w1 = (unsigned int)(v[i] >> 32);
          hw[base + i * 256] = (w0 >> 16) | (w1 & 0xFFFF0000u);
        }
      }
      __syncthreads();

#pragma unroll
      for (int ks = 0; ks < 16; ks++) {
        f16x8 a0 = *(const f16x8*)((char*)hs + (((ks * 4 + aq) * 32) + am) * 16);
        f16x8 a1 = *(const f16x8*)((char*)hs + (((ks * 4 + aq) * 32) + 16 + am) * 16);
        acc0 = __builtin_amdgcn_mfma_f32_16x16x32_f16(a0, bf[ks], acc0, 0, 0, 0);
        acc1 = __builtin_amdgcn_mfma_f32_16x16x32_f16(a1, bf[ks], acc1, 0, 0, 0);
      }
    }

#pragma unroll
    for (int r = 0; r < 4; r++) {
      int b = rbase + r;
      gbuf[gate][b][col]      = acc0[r] + gxr0[r];
      gbuf[gate][b + 16][col] = acc1[r] + gxr1[r];
    }
    __syncthreads();

    unsigned int* hwr = htag + (size_t)(s + 1) * SLOT32;
    int k = u0 + ul;
    float h0, h1;
    {
      float i_ = sigm(gbuf[0][b1][ul]), f_ = sigm(gbuf[1][b1][ul]);
      float g_ = tanh_(gbuf[2][b1][ul]), o_ = sigm(gbuf[3][b1][ul]);
      cst0 = f_ * cst0 + i_ * g_;
      h0 = o_ * tanh_(cst0);
      out[(size_t)(b1 * SEG + s) * HH + k] = h0;
    }
    {
      int b2 = b1 + 16;
      float i_ = sigm(gbuf[0][b2][ul]), f_ = sigm(gbuf[1][b2][ul]);
      float g_ = tanh_(gbuf[2][b2][ul]), o_ = sigm(gbuf[3][b2][ul]);
      cst1 = f_ * cst1 + i_ * g_;
      h1 = o_ * tanh_(cst1);
      out[(size_t)(b2 * SEG + s) * HH + k] = h1;
    }

    if (s < SEG - 1) {
      // publish tagged h[s+1]; fire-and-forget (no drain, no flag).
      // hs reuse is safe: next iteration's LDS writes come after this iteration's
      // MFMA reads (separated by the gbuf __syncthreads above).
      unsigned int tagn = (unsigned int)(s + 1);
      __hip_atomic_store(&hwr[((k >> 3) * 32 + b1) * 8 + (k & 7)],
                         (f16_bits((f16)h0) << 16) | tagn,
                         __ATOMIC_RELAXED, __HIP_MEMORY_SCOPE_AGENT);
      __hip_atomic_store(&hwr[((k >> 3) * 32 + (b1 + 16)) * 8 + (k & 7)],
                         (f16_bits((f16)h1) << 16) | tagn,
                         __ATOMIC_RELAXED, __HIP_MEMORY_SCOPE_AGENT);
    }
  }
}

// ---------------- launch ----------------
extern "C" void kernel_launch(void* const* d_in, const int* in_sizes, int n_in,
                              void* d_out, int out_size, void* d_ws, size_t ws_size,
                              hipStream_t stream) {
  const float* x    = (const float*)d_in[0];
  const float* w_ih = (const float*)d_in[1];
  const float* w_hh = (const float*)d_in[2];
  const float* b_ih = (const float*)d_in[3];
  const float* b_hh = (const float*)d_in[4];
  float* out = (float*)d_out;

  char* ws = (char*)d_ws;
  f16*   fhi   = (f16*)(ws + 0);            // 1664*2144*2 = 7,135,232
  f16*   w16   = (f16*)(ws + 7135232);      // 2048*2144*2 = 8,785,920
  f16*   whh16 = (f16*)(ws + 15921152);     // 2048*512*2 = 2,097,152
  float* gx    = (float*)(ws + 18018304);   // 1664*2048*4 = 13,631,488
  unsigned int* htag = (unsigned int*)(ws + 31649792);  // 50 slots x 64KB = 3,276,800

  // bit-exact replication of np.linspace(1,600,51) + Python round (half-even)
  TV tv;
  double step = 599.0 / 50.0;
  for (int i = 0; i <= 50; i++) {
    double v = (double)i * step + 1.0;
    tv.v[i] = (int)nearbyint(v);
  }
  tv.v[50] = 600;

  convert_kernel<<<dim3(2048), dim3(256), 0, stream>>>(
      (const float4*)w_ih, (const float4*)w_hh, (f16x4*)w16, (f16x4*)whh16);
  feats_kernel<<<dim3(MP), dim3(256), 0, stream>>>(x, fhi, tv);
  gemm_kernel<<<dim3(416), dim3(256), 0, stream>>>(fhi, w16, b_ih, b_hh, gx);

  void* args[] = { (void*)&gx, (void*)&whh16, (void*)&htag, (void*)&out };
  hipLaunchCooperativeKernel((void*)lstm_kernel, dim3(32), dim3(256), args, 0, stream);
}

// Round 6
// 298.678 us; speedup vs baseline: 1.3357x; 1.3357x over previous
//
#include <hip/hip_runtime.h>
#include <hip/hip_cooperative_groups.h>
#include <math.h>

namespace cg = cooperative_groups;

typedef _Float16 f16;
typedef _Float16 f16x8 __attribute__((ext_vector_type(8)));
typedef _Float16 f16x4 __attribute__((ext_vector_type(4)));
typedef float    f32x4 __attribute__((ext_vector_type(4)));

#define BATCH 32
#define TT    600
#define CC    64
#define SEG   50
#define HH    512
#define G4    2048
#define FF    2144   // IN_SIZE = 64 + 2080
#define MM    1600   // BATCH*SEG
#define MP    1664   // padded: 52*32 (s-major) = 26*64 M-tiles
#define NPAIR 2016   // C*(C-1)/2
#define CVB   512    // convert blocks appended to prep grid

struct TV { int v[51]; };

// async global->LDS, 16B per lane. LDS dest must be wave-uniform base + lane*16.
__device__ __forceinline__ void async_copy16(char* lds, const char* g) {
  __builtin_amdgcn_global_load_lds(
      (const __attribute__((address_space(1))) unsigned int*)g,
      (__attribute__((address_space(3))) unsigned int*)lds, 16, 0, 0);
}

__device__ __forceinline__ float sigm(float x) { return 1.f / (1.f + __expf(-x)); }
__device__ __forceinline__ float tanh_(float x) {
  float ax = fabsf(x);
  float e  = __expf(2.f * ax);
  float t  = 1.f - 2.f / (e + 1.f);   // robust for large |x|
  return x < 0.f ? -t : t;
}
__device__ __forceinline__ unsigned short f16_bits(f16 v) {
  union { f16 f; unsigned short u; } c; c.f = v; return c.u;
}

// ---------------- kernel 1: feats (blocks 0..MP-1) + weight convert (blocks MP..) ----
// s-major row layout: feature row m = s*32 + b
__global__ void prep_kernel(const float* __restrict__ x, f16* __restrict__ fhi, TV tv,
                            const float4* __restrict__ w_ih, const float4* __restrict__ w_hh,
                            f16x4* __restrict__ w16, f16x4* __restrict__ whh16,
                            unsigned int* __restrict__ ready) {
  __shared__ float xs[13 * CC];
  int m   = blockIdx.x;
  int tid = threadIdx.x;

  if (m >= MP) {              // ---- convert role ----
    int cb   = m - MP;
    int gtid = cb * 256 + tid;
    int nth  = CVB * 256;
    for (int i = gtid; i < G4 * FF / 4; i += nth) {
      float4 v = w_ih[i];
      f16x4 o = {(f16)v.x, (f16)v.y, (f16)v.z, (f16)v.w};
      w16[i] = o;
    }
    for (int i = gtid; i < G4 * HH / 4; i += nth) {
      float4 v = w_hh[i];
      f16x4 o = {(f16)v.x, (f16)v.y, (f16)v.z, (f16)v.w};
      whh16[i] = o;
    }
    if (cb == 0)               // zero the 32 ready slots (32 x 16 u32)
      for (int i = tid; i < 512; i += 256) ready[i] = 0u;
    return;
  }

  f16* rhi = fhi + (size_t)m * FF;
  if (m >= MM) {              // zero-pad rows 1600..1663 (s = 50,51) for the GEMM M-edge
    unsigned int* a = (unsigned int*)rhi;
    for (int i = tid; i < FF / 2; i += 256) a[i] = 0u;
    return;
  }
  int bb = m & 31, ss = m >> 5;
  int t0 = tv.v[ss] - 1, t1 = tv.v[ss + 1] - 1;
  int len = t1 - t0;          // #intervals in segment (11..12)
  for (int i = tid; i < (len + 1) * CC; i += 256)
    xs[i] = x[(size_t)bb * TT * CC + (size_t)(t0 + (i >> 6)) * CC + (i & 63)];
  __syncthreads();

  if (tid < CC) {             // inc (cols 0..63) and xa (cols 2080..2143)
    float xa  = xs[tid];
    float inc = xs[len * CC + tid] - xa;
    rhi[tid] = (f16)inc;
    rhi[2080 + tid] = (f16)xa;
  }

  int p0 = tid * 8;           // 252 threads x 8 pairs = 2016 upper-tri pairs
  if (p0 < NPAIR) {
    int c = 0, rem = p0;
    while (rem >= 63 - c) { rem -= 63 - c; c++; }
    int d = c + 1 + rem;
    int cs[8], dd[8];
#pragma unroll
    for (int i = 0; i < 8; i++) {
      cs[i] = c; dd[i] = d;
      d++; if (d == 64) { c++; d = c + 1; }
    }
    float acc[8], xc[8], xd[8];
#pragma unroll
    for (int i = 0; i < 8; i++) { acc[i] = 0.f; xc[i] = xs[cs[i]]; xd[i] = xs[dd[i]]; }
    for (int t = 1; t <= len; t++) {
#pragma unroll
      for (int i = 0; i < 8; i++) {      // Levy area: sum x_c*dx_d - x_d*dx_c
        float nc = xs[t * CC + cs[i]], nd = xs[t * CC + dd[i]];
        acc[i] += xc[i] * (nd - xd[i]) - xd[i] * (nc - xc[i]);
        xc[i] = nc; xd[i] = nd;
      }
    }
#pragma unroll
    for (int i = 0; i < 8; i++) {
      int ci = cs[i], di = dd[i];
      float xac = xs[ci], xad = xs[di];
      float incc = xs[len * CC + ci] - xac, incd = xs[len * CC + di] - xad;
      float v = 0.5f * acc[i] - 0.5f * (xac * incd - xad * incc);
      rhi[64 + p0 + i] = (f16)v;
    }
  }
}

// ---------------- kernel 2: gx = feats @ w_ih^T + bias  (64x128 tiles, 416 blocks) ----
// XCD swizzle: per XCD, its 52 blocks cover all 26 M-tiles x 2 N-stripes -> B stays
// L2-resident. Wave wn owns a 64x32 sub-tile. Single fp16 pass.
__global__ __launch_bounds__(256) void gemm_kernel(
    const f16* __restrict__ fhi, const f16* __restrict__ w16,
    const float* __restrict__ bih, const float* __restrict__ bhh,
    float* __restrict__ gx) {
  __shared__ f16 smem[6 * 1024];   // A(4K) | B(8K)
  int tid  = threadIdx.x;
  int lane = tid & 63;
  int wn   = tid >> 6;

  int id = blockIdx.x;
  int x8 = id & 7;
  int j  = id >> 3;            // 0..51
  int mt = j % 26;
  int nt = (x8 << 1) | (j / 26);
  int m0 = mt * 64;
  int n0 = nt * 128;

  char* ldsA = (char*)&smem[0];
  char* ldsB = (char*)&smem[2048];

  int rowq = tid >> 2;            // 0..63
  int colq = (tid & 3) * 8;       // halves
  const f16* pa  = fhi + (size_t)(m0 + rowq) * FF + colq;
  const f16* pb0 = w16 + (size_t)(n0 + rowq) * FF + colq;
  const f16* pb1 = pb0 + (size_t)64 * FF;
  int ldst = tid * 16;

  f32x4 zero4 = {0.f, 0.f, 0.f, 0.f};
  f32x4 acc[4][2];
#pragma unroll
  for (int i = 0; i < 4; i++) { acc[i][0] = zero4; acc[i][1] = zero4; }

  int quad16 = (lane >> 4) * 16;  // byte offset of k-slice in a row
  int am = lane & 15;

  for (int kt = 0; kt < FF / 32; kt++) {
    int koff = kt * 32;
    async_copy16(ldsA + ldst,        (const char*)(pa + koff));
    async_copy16(ldsB + ldst,        (const char*)(pb0 + koff));
    async_copy16(ldsB + 4096 + ldst, (const char*)(pb1 + koff));
    __syncthreads();

    f16x8 bfr[2];
#pragma unroll
    for (int ni = 0; ni < 2; ni++)
      bfr[ni] = *(const f16x8*)(ldsB + (wn * 32 + ni * 16 + am) * 64 + quad16);
#pragma unroll
    for (int mi = 0; mi < 4; mi++) {
      f16x8 ah = *(const f16x8*)(ldsA + (mi * 16 + am) * 64 + quad16);
#pragma unroll
      for (int ni = 0; ni < 2; ni++)
        acc[mi][ni] = __builtin_amdgcn_mfma_f32_16x16x32_f16(ah, bfr[ni], acc[mi][ni], 0, 0, 0);
    }
    __syncthreads();
  }

#pragma unroll
  for (int ni = 0; ni < 2; ni++) {
    int ncol = n0 + wn * 32 + ni * 16 + (lane & 15);
    float bv = bih[ncol] + bhh[ncol];
#pragma unroll
    for (int mi = 0; mi < 4; mi++) {
      int mrow = m0 + mi * 16 + (lane >> 4) * 4;
#pragma unroll
      for (int r = 0; r < 4; r++)
        gx[(size_t)(mrow + r) * G4 + ncol] = acc[mi][ni][r] + bv;
    }
  }
}

// ---------------- kernel 3: persistent LSTM, flag protocol, 1-wave/SIMD VGPR budget ----
// 32 WGs x 256 thr (1 WG/CU -> 1 wave/SIMD). __launch_bounds__(256,1) gives the
// full 512-VGPR budget so the 32KB h staging is ONE batch of 16 u64 coherent loads
// (single L3 round-trip) instead of compiler-serialized batches (R2/R3 defect).
__global__ __launch_bounds__(256, 1) void lstm_kernel(
    const float* __restrict__ gx, const f16* __restrict__ whh16,
    unsigned short* __restrict__ hbuf, unsigned int* __restrict__ ready,
    float* __restrict__ out) {
  __shared__ f16 hs[BATCH * HH];         // 32 KB, layout [k8][b][8] fp16
  __shared__ float gbuf[4][BATCH][16];   // 8 KB gate exchange

  int tid  = threadIdx.x;
  int lane = tid & 63;
  int gate = tid >> 6;
  int u0   = blockIdx.x * 16;
  int wg   = blockIdx.x;

  // preload w_hh fragments: B[k][n] = w_hh[n][k], n = gate*512 + u0 + (lane&15)
  f16x8 bf[16];
  {
    const f16* wrow = whh16 + (size_t)(gate * HH + u0 + (lane & 15)) * HH + (lane >> 4) * 8;
#pragma unroll
    for (int ks = 0; ks < 16; ks++) bf[ks] = *(const f16x8*)(wrow + ks * 32);
  }

  int b1 = tid >> 4;
  int ul = tid & 15;
  float cst0 = 0.f, cst1 = 0.f;
  int aq  = (lane >> 4);
  int am  = (lane & 15);
  int col = lane & 15;
  int rbase = (lane >> 4) * 4;

  for (int s = 0; s < SEG; s++) {
    // prefetch gx for this step (independent of h -> in flight across the poll)
    float gxr0[4], gxr1[4];
#pragma unroll
    for (int r = 0; r < 4; r++) {
      int b = rbase + r;
      gxr0[r] = gx[(size_t)((s << 5) + b) * G4 + gate * HH + u0 + col];
      gxr1[r] = gx[(size_t)((s << 5) + b + 16) * G4 + gate * HH + u0 + col];
    }

    f32x4 acc0 = {0.f, 0.f, 0.f, 0.f};
    f32x4 acc1 = {0.f, 0.f, 0.f, 0.f};

    if (s > 0) {
      // wait: all 32 WGs published h[s]
      unsigned int tgt = (unsigned int)s;
      if (tid < 32) {
        while (__hip_atomic_load(&ready[tid * 16], __ATOMIC_RELAXED,
                                 __HIP_MEMORY_SCOPE_AGENT) < tgt)
          __builtin_amdgcn_s_sleep(1);
      }
      __syncthreads();

      // stage h[s] -> LDS: 16 u64 coherent loads, ONE batch (512-VGPR budget)
      const unsigned long long* hrd =
          (const unsigned long long*)(hbuf + (size_t)(s & 1) * (BATCH * HH));
      unsigned long long v[16];
#pragma unroll
      for (int i = 0; i < 16; i++)
        v[i] = __hip_atomic_load(hrd + i * 256 + tid, __ATOMIC_RELAXED,
                                 __HIP_MEMORY_SCOPE_AGENT);
      unsigned long long* hw = (unsigned long long*)hs;
#pragma unroll
      for (int i = 0; i < 16; i++) hw[i * 256 + tid] = v[i];
      __syncthreads();

#pragma unroll
      for (int ks = 0; ks < 16; ks++) {
        f16x8 a0 = *(const f16x8*)((char*)hs + (((ks * 4 + aq) * 32) + am) * 16);
        f16x8 a1 = *(const f16x8*)((char*)hs + (((ks * 4 + aq) * 32) + 16 + am) * 16);
        acc0 = __builtin_amdgcn_mfma_f32_16x16x32_f16(a0, bf[ks], acc0, 0, 0, 0);
        acc1 = __builtin_amdgcn_mfma_f32_16x16x32_f16(a1, bf[ks], acc1, 0, 0, 0);
      }
    }

#pragma unroll
    for (int r = 0; r < 4; r++) {
      int b = rbase + r;
      gbuf[gate][b][col]      = acc0[r] + gxr0[r];
      gbuf[gate][b + 16][col] = acc1[r] + gxr1[r];
    }
    __syncthreads();

    unsigned short* hwr = hbuf + (size_t)((s + 1) & 1) * (BATCH * HH);
    int k = u0 + ul;
    float h0, h1;
    {
      float i_ = sigm(gbuf[0][b1][ul]), f_ = sigm(gbuf[1][b1][ul]);
      float g_ = tanh_(gbuf[2][b1][ul]), o_ = sigm(gbuf[3][b1][ul]);
      cst0 = f_ * cst0 + i_ * g_;
      h0 = o_ * tanh_(cst0);
      out[(size_t)(b1 * SEG + s) * HH + k] = h0;
    }
    {
      int b2 = b1 + 16;
      float i_ = sigm(gbuf[0][b2][ul]), f_ = sigm(gbuf[1][b2][ul]);
      float g_ = tanh_(gbuf[2][b2][ul]), o_ = sigm(gbuf[3][b2][ul]);
      cst1 = f_ * cst1 + i_ * g_;
      h1 = o_ * tanh_(cst1);
      out[(size_t)(b2 * SEG + s) * HH + k] = h1;
    }

    if (s < SEG - 1) {
      // publish h[s+1] via coherent u16 stores; __syncthreads drains vmcnt(0)
      // (compiler emits s_waitcnt vmcnt(0) before s_barrier), so stores are acked
      // at the coherence point before the flag goes out.
      __hip_atomic_store(hwr + ((k >> 3) * 32 + b1) * 8 + (k & 7),
                         f16_bits((f16)h0), __ATOMIC_RELAXED, __HIP_MEMORY_SCOPE_AGENT);
      __hip_atomic_store(hwr + ((k >> 3) * 32 + (b1 + 16)) * 8 + (k & 7),
                         f16_bits((f16)h1), __ATOMIC_RELAXED, __HIP_MEMORY_SCOPE_AGENT);
      __syncthreads();
      if (tid == 0)
        __hip_atomic_store(&ready[wg * 16], (unsigned int)(s + 1),
                           __ATOMIC_RELAXED, __HIP_MEMORY_SCOPE_AGENT);
    }
  }
}

// ---------------- launch ----------------
extern "C" void kernel_launch(void* const* d_in, const int* in_sizes, int n_in,
                              void* d_out, int out_size, void* d_ws, size_t ws_size,
                              hipStream_t stream) {
  const float* x    = (const float*)d_in[0];
  const float* w_ih = (const float*)d_in[1];
  const float* w_hh = (const float*)d_in[2];
  const float* b_ih = (const float*)d_in[3];
  const float* b_hh = (const float*)d_in[4];
  float* out = (float*)d_out;

  char* ws = (char*)d_ws;
  f16*   fhi   = (f16*)(ws + 0);            // 1664*2144*2 = 7,135,232
  f16*   w16   = (f16*)(ws + 7135232);      // 2048*2144*2 = 8,785,920
  f16*   whh16 = (f16*)(ws + 15921152);     // 2048*512*2 = 2,097,152
  float* gx    = (float*)(ws + 18018304);   // 1664*2048*4 = 13,631,488
  unsigned short* hbuf  = (unsigned short*)(ws + 31649792); // 2*32KB ping-pong
  unsigned int*   ready = (unsigned int*)(ws + 31715328);   // 32 slots x 64B

  // bit-exact replication of np.linspace(1,600,51) + Python round (half-even)
  TV tv;
  double step = 599.0 / 50.0;
  for (int i = 0; i <= 50; i++) {
    double v = (double)i * step + 1.0;
    tv.v[i] = (int)nearbyint(v);
  }
  tv.v[50] = 600;

  prep_kernel<<<dim3(MP + CVB), dim3(256), 0, stream>>>(
      x, fhi, tv, (const float4*)w_ih, (const float4*)w_hh,
      (f16x4*)w16, (f16x4*)whh16, ready);
  gemm_kernel<<<dim3(416), dim3(256), 0, stream>>>(fhi, w16, b_ih, b_hh, gx);

  void* args[] = { (void*)&gx, (void*)&whh16, (void*)&hbuf, (void*)&ready, (void*)&out };
  hipLaunchCooperativeKernel((void*)lstm_kernel, dim3(32), dim3(256), args, 0, stream);
}